// Round 5
// baseline (1174.312 us; speedup 1.0000x reference)
//
#include <hip/hip_runtime.h>
#include <math.h>

// Fused separable multi-Gaussian, one LDS array, register scatter-accumulation.
// Round-5 == Round-4 resubmit (round-4 bench died to an infra error, not the
// kernel). Occupancy-first: RPT=2 shrinks live registers to fit the 64-VGPR
// occupancy step (8 waves/SIMD via __launch_bounds__(256,8)); rounds 2/3
// proved the fused design latency-bound at ~2 waves/SIMD (VGPR 92-108,
// occupancy 22%, VALUBusy 30%). LDS re-reads rise (48 B/px vs 30) but the LDS
// pipe has headroom; the win is 4x more waves to hide LDS+HBM latency.
//
// Tile: 256 wide x 8 tall outputs per 256-thread block.
// Thread: 4 cols (float4) x 2 rows. Wave = 64 lanes on ONE row (contiguous
// 1024B LDS reads, conflict-free by construction).
#define TX   256
#define RPT  2                 // output rows per thread
#define TYB  8                 // output rows per block (4 y-groups * RPT)
#define IN_W 264               // TX + 8 (x-halo 4 each side, float4-aligned; conv needs 3)
#define IN_H (TYB + 6)         // 14 (y-halo 3 each side)

struct GaussCoefs {
    float g3[3];
    float g5[5];
    float g7[7];
};

// Wave-uniform float -> SGPR (frees a VGPR for the whole kernel).
__device__ __forceinline__ float rfl(float x) {
    return __int_as_float(__builtin_amdgcn_readfirstlane(__float_as_int(x)));
}

// acc.{xyzw} += W * F.{xyzw}
#define ADD4(A, W, F) \
    A.x = fmaf((W), (F).x, A.x); A.y = fmaf((W), (F).y, A.y); \
    A.z = fmaf((W), (F).z, A.z); A.w = fmaf((W), (F).w, A.w);

#define DOT7(a,b,c,d,e,f,g) \
    fmaf(g7h0,(a), fmaf(g7h1,(b), fmaf(g7h2,(c), fmaf(g7h3,(d), \
    fmaf(g7h4,(e), fmaf(g7h5,(f), (g7h6)*(g)))))))
#define DOT5(a,b,c,d,e) \
    fmaf(g5h0,(a), fmaf(g5h1,(b), fmaf(g5h2,(c), fmaf(g5h3,(d), (g5h4)*(e)))))
#define DOT3(a,b,c) \
    fmaf(g3h0,(a), fmaf(g3h1,(b), (g3h2)*(c)))

// Load one input row (12 floats, 3 contiguous ds_read_b128) into named regs.
#define LOADROW(RI) \
    const float* row_ = &in_tile[ty0 + (RI)][xb]; \
    const float4 va = *(const float4*)(row_); \
    const float4 vb = *(const float4*)(row_ + 4); \
    const float4 vc = *(const float4*)(row_ + 8); \
    const float v1 = va.y, v2 = va.z, v3 = va.w; \
    const float v4 = vb.x, v5 = vb.y, v6 = vb.z, v7 = vb.w; \
    const float v8 = vc.x, v9 = vc.y, v10 = vc.z; \
    (void)v10;

#define CALC_H7 \
    float4 h7; \
    h7.x = DOT7(v1,v2,v3,v4,v5,v6,v7); \
    h7.y = DOT7(v2,v3,v4,v5,v6,v7,v8); \
    h7.z = DOT7(v3,v4,v5,v6,v7,v8,v9); \
    h7.w = DOT7(v4,v5,v6,v7,v8,v9,v10);

#define CALC_H5 \
    float4 h5; \
    h5.x = DOT5(v2,v3,v4,v5,v6); \
    h5.y = DOT5(v3,v4,v5,v6,v7); \
    h5.z = DOT5(v4,v5,v6,v7,v8); \
    h5.w = DOT5(v5,v6,v7,v8,v9);

#define CALC_H3 \
    float4 h3; \
    h3.x = DOT3(v3,v4,v5); \
    h3.y = DOT3(v4,v5,v6); \
    h3.z = DOT3(v5,v6,v7); \
    h3.w = DOT3(v6,v7,v8);

#define SVEC make_float4(v4, v5, v6, v7)

__global__ __launch_bounds__(256, 8) void mgdf_kernel(
    const float* __restrict__ s,
    const float* __restrict__ w1p, const float* __restrict__ w2p,
    const float* __restrict__ w3p, const float* __restrict__ w4p,
    float* __restrict__ out,
    GaussCoefs gc, int Wd, int Hd)
{
    __shared__ float in_tile[IN_H][IN_W];

    const int tid   = threadIdx.x;
    const int plane = blockIdx.z;          // b*C + c
    const int x0    = blockIdx.x * TX;
    const int y0    = blockIdx.y * TYB;
    const float* sp = s + (size_t)plane * Hd * Wd;

    // Fold diff chain: (w1+w2)*s + (w3-w2)*s3 + (w4-w3)*s5 + (-w4)*s7
    const float w1 = *w1p, w2 = *w2p, w3 = *w3p, w4 = *w4p;
    const float a0v = w1 + w2;
    const float a3v = w3 - w2;
    const float a5v = w4 - w3;
    const float a7v = -w4;

    // Horizontal (unscaled) coefficients: kernarg -> SGPR already.
    const float g7h0 = gc.g7[0], g7h1 = gc.g7[1], g7h2 = gc.g7[2],
                g7h3 = gc.g7[3], g7h4 = gc.g7[4], g7h5 = gc.g7[5],
                g7h6 = gc.g7[6];
    const float g5h0 = gc.g5[0], g5h1 = gc.g5[1], g5h2 = gc.g5[2],
                g5h3 = gc.g5[3], g5h4 = gc.g5[4];
    const float g3h0 = gc.g3[0], g3h1 = gc.g3[1], g3h2 = gc.g3[2];

    // Vertical coefficients pre-scaled by fold weights; wave-uniform -> SGPR.
    const float a0   = rfl(a0v);
    const float w7v0 = rfl(a7v * g7h0), w7v1 = rfl(a7v * g7h1),
                w7v2 = rfl(a7v * g7h2), w7v3 = rfl(a7v * g7h3),
                w7v4 = rfl(a7v * g7h4), w7v5 = rfl(a7v * g7h5),
                w7v6 = rfl(a7v * g7h6);
    const float w5v0 = rfl(a5v * g5h0), w5v1 = rfl(a5v * g5h1),
                w5v2 = rfl(a5v * g5h2), w5v3 = rfl(a5v * g5h3),
                w5v4 = rfl(a5v * g5h4);
    const float w3v0 = rfl(a3v * g3h0), w3v1 = rfl(a3v * g3h1),
                w3v2 = rfl(a3v * g3h2);

    // ---- Stage input tile (halo, zero-padded at image borders) ----
    // 14 rows x 66 float4 chunks = 924 tasks; LDS address is linear in task
    // id (16*c bytes) -> contiguous, conflict-free writes.
    for (int c = tid; c < IN_H * (IN_W / 4); c += 256) {
        const int r  = c / (IN_W / 4);
        const int c4 = c % (IN_W / 4);
        const int gy = y0 - 3 + r;
        const int gx = x0 - 4 + c4 * 4;
        float4 v = make_float4(0.f, 0.f, 0.f, 0.f);
        if (gy >= 0 && gy < Hd) {
            const float* rowp = sp + (size_t)gy * Wd;
            if (gx >= 0 && gx + 3 < Wd) {
                v = *(const float4*)(rowp + gx);
            } else {
                float tmp[4];
                #pragma unroll
                for (int j = 0; j < 4; ++j) {
                    const int x = gx + j;
                    tmp[j] = (x >= 0 && x < Wd) ? rowp[x] : 0.f;
                }
                v = make_float4(tmp[0], tmp[1], tmp[2], tmp[3]);
            }
        }
        *(float4*)&in_tile[r][c4 * 4] = v;
    }
    __syncthreads();

    // ---- Fused horizontal + vertical pass, fully straight-line ----
    const int tx  = tid & 63;      // x chunk (float4): whole wave on one row
    const int tyg = tid >> 6;      // y group == wave id (0..3)
    const int ty0 = tyg * RPT;     // first output row (tile-local)
    const int xb  = tx * 4;

    float4 acc0 = make_float4(0.f, 0.f, 0.f, 0.f);
    float4 acc1 = make_float4(0.f, 0.f, 0.f, 0.f);

    // Output row yo consumes input rows yo+iv (iv=0..6):
    //   h7: w7v[iv] (0..6) | h5: w5v[iv-1] (1..5) | h3: w3v[iv-2] (2..4) | s: a0 (iv==3)
    // Edge steps skip unused h5/h3 computation entirely.
    { LOADROW(0); CALC_H7;
      ADD4(acc0, w7v0, h7); }
    { LOADROW(1); CALC_H7; CALC_H5;
      ADD4(acc0, w7v1, h7); ADD4(acc0, w5v0, h5);
      ADD4(acc1, w7v0, h7); }
    { LOADROW(2); CALC_H7; CALC_H5; CALC_H3;
      ADD4(acc0, w7v2, h7); ADD4(acc0, w5v1, h5); ADD4(acc0, w3v0, h3);
      ADD4(acc1, w7v1, h7); ADD4(acc1, w5v0, h5); }
    { LOADROW(3); CALC_H7; CALC_H5; CALC_H3;
      ADD4(acc0, w7v3, h7); ADD4(acc0, w5v2, h5); ADD4(acc0, w3v1, h3); ADD4(acc0, a0, SVEC);
      ADD4(acc1, w7v2, h7); ADD4(acc1, w5v1, h5); ADD4(acc1, w3v0, h3); }
    { LOADROW(4); CALC_H7; CALC_H5; CALC_H3;
      ADD4(acc0, w7v4, h7); ADD4(acc0, w5v3, h5); ADD4(acc0, w3v2, h3);
      ADD4(acc1, w7v3, h7); ADD4(acc1, w5v2, h5); ADD4(acc1, w3v1, h3); ADD4(acc1, a0, SVEC); }
    { LOADROW(5); CALC_H7; CALC_H5; CALC_H3;
      ADD4(acc0, w7v5, h7); ADD4(acc0, w5v4, h5);
      ADD4(acc1, w7v4, h7); ADD4(acc1, w5v3, h5); ADD4(acc1, w3v2, h3); }
    { LOADROW(6); CALC_H7; CALC_H5;
      ADD4(acc0, w7v6, h7);
      ADD4(acc1, w7v5, h7); ADD4(acc1, w5v4, h5); }
    { LOADROW(7); CALC_H7;
      ADD4(acc1, w7v6, h7); }

    // ---- Store (wave lanes -> 1024 consecutive bytes per row) ----
    float* outp = out + (size_t)plane * Hd * Wd + (size_t)x0 + xb;
    const int gy0 = y0 + ty0;
    if (x0 + xb < Wd) {
        if (gy0 + 0 < Hd) *(float4*)(outp + (size_t)(gy0 + 0) * Wd) = acc0;
        if (gy0 + 1 < Hd) *(float4*)(outp + (size_t)(gy0 + 1) * Wd) = acc1;
    }
}

static void fill_gauss(float* g, int k) {
    const double sigma = 0.3 * ((k - 1) * 0.5 - 1.0) + 0.8;
    double t[7], sum = 0.0;
    for (int i = 0; i < k; ++i) {
        const double x = (double)(i - k / 2);
        t[i] = exp(-x * x / (2.0 * sigma * sigma));
        sum += t[i];
    }
    for (int i = 0; i < k; ++i) g[i] = (float)(t[i] / sum);
}

extern "C" void kernel_launch(void* const* d_in, const int* in_sizes, int n_in,
                              void* d_out, int out_size, void* d_ws, size_t ws_size,
                              hipStream_t stream) {
    const float* s  = (const float*)d_in[0];
    const float* w1 = (const float*)d_in[1];
    const float* w2 = (const float*)d_in[2];
    const float* w3 = (const float*)d_in[3];
    const float* w4 = (const float*)d_in[4];
    float* out = (float*)d_out;

    const int Hd = 512, Wd = 512;
    const int planes = in_sizes[0] / (Hd * Wd);   // B*C = 192

    GaussCoefs gc;
    fill_gauss(gc.g3, 3);
    fill_gauss(gc.g5, 5);
    fill_gauss(gc.g7, 7);

    dim3 grid((Wd + TX - 1) / TX, (Hd + TYB - 1) / TYB, planes);
    mgdf_kernel<<<grid, 256, 0, stream>>>(s, w1, w2, w3, w4, out, gc, Wd, Hd);
}

// Round 6
// 370.227 us; speedup vs baseline: 3.1719x; 3.1719x over previous
//
#include <hip/hip_runtime.h>
#include <math.h>

// Global-direct column-march multi-Gaussian fusion. No LDS, no barriers.
// Each thread owns 4 cols (float4) x STRIP_H rows and marches down the strip:
// per input row it loads 12 floats (3x float4, L1/L2-resident), computes the
// three horizontal convolutions ONCE, and scatters them into a ring of 8
// named float4 accumulators (sliding window over 7 pending output rows).
// Ring rotation is done by macro-argument permutation -> zero v_movs, zero
// runtime indexing (round-1 lesson), small natural VGPR set (round-5 lesson:
// never force occupancy via launch_bounds; earn it with a small live set).
//
// Block: 256 threads = 4 independent waves: (2 x-halves) x (2 y-strips).
// Wave = 64 lanes x 4 px = 256 px of one row-strip. Grid: (1, H/64, planes).
#define STRIP_H 32

struct GaussCoefs { float g3[3]; float g5[5]; float g7[7]; };

// Wave-uniform float -> SGPR.
__device__ __forceinline__ float rfl(float x) {
    return __int_as_float(__builtin_amdgcn_readfirstlane(__float_as_int(x)));
}

#define Z4 make_float4(0.f, 0.f, 0.f, 0.f)

// acc.{xyzw} += W * F.{xyzw}
#define ADD4(A, W, F) \
    A.x = fmaf((W), (F).x, A.x); A.y = fmaf((W), (F).y, A.y); \
    A.z = fmaf((W), (F).z, A.z); A.w = fmaf((W), (F).w, A.w);

#define DOT7(a,b,c,d,e,f,g) \
    fmaf(g7h0,(a), fmaf(g7h1,(b), fmaf(g7h2,(c), fmaf(g7h3,(d), \
    fmaf(g7h4,(e), fmaf(g7h5,(f), (g7h6)*(g)))))))
#define DOT5(a,b,c,d,e) \
    fmaf(g5h0,(a), fmaf(g5h1,(b), fmaf(g5h2,(c), fmaf(g5h3,(d), (g5h4)*(e)))))
#define DOT3(a,b,c) \
    fmaf(g3h0,(a), fmaf(g3h1,(b), (g3h2)*(c)))

// Load one input row: 3 float4 at x = xb-4 / xb / xb+4. Edge lanes use a
// clamped offset and get zeroed via cndmask (killA/killC are per-thread
// constants). y-OOB rows (zero padding) take a wave-uniform scalar branch.
#define LOADR(vA, vB, vC) \
    float4 vA, vB, vC; \
    if ((unsigned)row < (unsigned)Hd) { \
        const float* rp_ = sp + row * Wd; \
        vA = *(const float4*)(rp_ + offA); \
        vB = *(const float4*)(rp_ + offB); \
        vC = *(const float4*)(rp_ + offC); \
        if (killA) vA = Z4; \
        if (killC) vC = Z4; \
    } else { vA = Z4; vB = Z4; vC = Z4; } \
    ++row;

// Horizontal convolutions for 4 outputs centered at vB (x = xb..xb+3).
#define H7CALC(vA,vB,vC,h7) float4 h7; \
    h7.x = DOT7(vA.y,vA.z,vA.w,vB.x,vB.y,vB.z,vB.w); \
    h7.y = DOT7(vA.z,vA.w,vB.x,vB.y,vB.z,vB.w,vC.x); \
    h7.z = DOT7(vA.w,vB.x,vB.y,vB.z,vB.w,vC.x,vC.y); \
    h7.w = DOT7(vB.x,vB.y,vB.z,vB.w,vC.x,vC.y,vC.z);
#define H5CALC(vA,vB,vC,h5) float4 h5; \
    h5.x = DOT5(vA.z,vA.w,vB.x,vB.y,vB.z); \
    h5.y = DOT5(vA.w,vB.x,vB.y,vB.z,vB.w); \
    h5.z = DOT5(vB.x,vB.y,vB.z,vB.w,vC.x); \
    h5.w = DOT5(vB.y,vB.z,vB.w,vC.x,vC.y);
#define H3CALC(vA,vB,vC,h3) float4 h3; \
    h3.x = DOT3(vA.w,vB.x,vB.y); \
    h3.y = DOT3(vB.x,vB.y,vB.z); \
    h3.z = DOT3(vB.y,vB.z,vB.w); \
    h3.w = DOT3(vB.z,vB.w,vC.x);

// Steady-state step at input row r: scatter to 7 pending outputs (S0 = oldest,
// o = r-6, completed this step), store S0, zero it for reuse as o = r+2's slot.
//   h7 -> S0..S6 with w7v6..w7v0 | h5 -> S1..S5 with w5v4..w5v0
//   h3 -> S2..S4 with w3v2..w3v0 | s (=vB) -> S3 with a0
#define MAINSTEP(S0,S1,S2,S3,S4,S5,S6) { \
    LOADR(vA, vB, vC); \
    H7CALC(vA,vB,vC,h7); H5CALC(vA,vB,vC,h5); H3CALC(vA,vB,vC,h3); \
    ADD4(S0, w7v6, h7); ADD4(S1, w7v5, h7); ADD4(S2, w7v4, h7); \
    ADD4(S3, w7v3, h7); ADD4(S4, w7v2, h7); ADD4(S5, w7v1, h7); \
    ADD4(S6, w7v0, h7); \
    ADD4(S1, w5v4, h5); ADD4(S2, w5v3, h5); ADD4(S3, w5v2, h5); \
    ADD4(S4, w5v1, h5); ADD4(S5, w5v0, h5); \
    ADD4(S2, w3v2, h3); ADD4(S3, w3v1, h3); ADD4(S4, w3v0, h3); \
    ADD4(S3, a0, vB); \
    *(float4*)(op + orow * Wd + xb) = S0; \
    S0 = Z4; ++orow; }

__global__ __launch_bounds__(256, 4) void mgdf_kernel(
    const float* __restrict__ s,
    const float* __restrict__ w1p, const float* __restrict__ w2p,
    const float* __restrict__ w3p, const float* __restrict__ w4p,
    float* __restrict__ out,
    GaussCoefs gc, int Wd, int Hd)
{
    const int tid  = threadIdx.x;
    const int lane = tid & 63;
    const int xh   = (tid >> 6) & 1;    // x half (0: px 0..255, 1: 256..511)
    const int ysub = tid >> 7;          // y strip within block (0/1)
    const int plane = blockIdx.z;
    const int xb   = xh * 256 + lane * 4;
    const int ys0  = (blockIdx.y * 2 + ysub) * STRIP_H;

    const float* sp = s + (size_t)plane * Hd * Wd;
    float*       op = out + (size_t)plane * Hd * Wd;

    // Fold diff chain: (w1+w2)*s + (w3-w2)*s3 + (w4-w3)*s5 + (-w4)*s7
    const float w1 = *w1p, w2 = *w2p, w3 = *w3p, w4 = *w4p;
    const float a0v = w1 + w2, a3v = w3 - w2, a5v = w4 - w3, a7v = -w4;

    // Horizontal (unscaled) coefficients: kernarg -> SGPR already.
    const float g7h0 = gc.g7[0], g7h1 = gc.g7[1], g7h2 = gc.g7[2],
                g7h3 = gc.g7[3], g7h4 = gc.g7[4], g7h5 = gc.g7[5],
                g7h6 = gc.g7[6];
    const float g5h0 = gc.g5[0], g5h1 = gc.g5[1], g5h2 = gc.g5[2],
                g5h3 = gc.g5[3], g5h4 = gc.g5[4];
    const float g3h0 = gc.g3[0], g3h1 = gc.g3[1], g3h2 = gc.g3[2];

    // Vertical coefficients pre-scaled by fold weights; wave-uniform -> SGPR.
    const float a0   = rfl(a0v);
    const float w7v0 = rfl(a7v * g7h0), w7v1 = rfl(a7v * g7h1),
                w7v2 = rfl(a7v * g7h2), w7v3 = rfl(a7v * g7h3),
                w7v4 = rfl(a7v * g7h4), w7v5 = rfl(a7v * g7h5),
                w7v6 = rfl(a7v * g7h6);
    const float w5v0 = rfl(a5v * g5h0), w5v1 = rfl(a5v * g5h1),
                w5v2 = rfl(a5v * g5h2), w5v3 = rfl(a5v * g5h3),
                w5v4 = rfl(a5v * g5h4);
    const float w3v0 = rfl(a3v * g3h0), w3v1 = rfl(a3v * g3h1),
                w3v2 = rfl(a3v * g3h2);

    // x-halo handling: halo is exactly one float4, OOB only for the extreme
    // lane of the extreme half. Clamp the offset, zero after load.
    const bool killA = (xb - 4) < 0;          // xh==0, lane 0 only
    const bool killC = (xb + 7) >= Wd;        // xh==1, lane 63 only
    const int offA = killA ? xb : (xb - 4);
    const int offB = xb;
    const int offC = killC ? xb : (xb + 4);

    int row  = ys0 - 3;   // next input row to load (global y)
    int orow = ys0;       // next output row to store (global y)

    float4 A0 = Z4, A1 = Z4, A2 = Z4, A3 = Z4,
           A4 = Z4, A5 = Z4, A6 = Z4, A7 = Z4;

    // ---- Prologue: input rows r = 0..5, partial scatter (outputs >= 0) ----
    { LOADR(vA,vB,vC); H7CALC(vA,vB,vC,h7);
      ADD4(A0, w7v0, h7); }
    { LOADR(vA,vB,vC); H7CALC(vA,vB,vC,h7); H5CALC(vA,vB,vC,h5);
      ADD4(A1, w7v0, h7); ADD4(A0, w7v1, h7);
      ADD4(A0, w5v0, h5); }
    { LOADR(vA,vB,vC); H7CALC(vA,vB,vC,h7); H5CALC(vA,vB,vC,h5); H3CALC(vA,vB,vC,h3);
      ADD4(A2, w7v0, h7); ADD4(A1, w7v1, h7); ADD4(A0, w7v2, h7);
      ADD4(A1, w5v0, h5); ADD4(A0, w5v1, h5);
      ADD4(A0, w3v0, h3); }
    { LOADR(vA,vB,vC); H7CALC(vA,vB,vC,h7); H5CALC(vA,vB,vC,h5); H3CALC(vA,vB,vC,h3);
      ADD4(A3, w7v0, h7); ADD4(A2, w7v1, h7); ADD4(A1, w7v2, h7); ADD4(A0, w7v3, h7);
      ADD4(A2, w5v0, h5); ADD4(A1, w5v1, h5); ADD4(A0, w5v2, h5);
      ADD4(A1, w3v0, h3); ADD4(A0, w3v1, h3);
      ADD4(A0, a0, vB); }
    { LOADR(vA,vB,vC); H7CALC(vA,vB,vC,h7); H5CALC(vA,vB,vC,h5); H3CALC(vA,vB,vC,h3);
      ADD4(A4, w7v0, h7); ADD4(A3, w7v1, h7); ADD4(A2, w7v2, h7);
      ADD4(A1, w7v3, h7); ADD4(A0, w7v4, h7);
      ADD4(A3, w5v0, h5); ADD4(A2, w5v1, h5); ADD4(A1, w5v2, h5); ADD4(A0, w5v3, h5);
      ADD4(A2, w3v0, h3); ADD4(A1, w3v1, h3); ADD4(A0, w3v2, h3);
      ADD4(A1, a0, vB); }
    { LOADR(vA,vB,vC); H7CALC(vA,vB,vC,h7); H5CALC(vA,vB,vC,h5); H3CALC(vA,vB,vC,h3);
      ADD4(A5, w7v0, h7); ADD4(A4, w7v1, h7); ADD4(A3, w7v2, h7);
      ADD4(A2, w7v3, h7); ADD4(A1, w7v4, h7); ADD4(A0, w7v5, h7);
      ADD4(A4, w5v0, h5); ADD4(A3, w5v1, h5); ADD4(A2, w5v2, h5);
      ADD4(A1, w5v3, h5); ADD4(A0, w5v4, h5);
      ADD4(A3, w3v0, h3); ADD4(A2, w3v1, h3); ADD4(A1, w3v2, h3);
      ADD4(A2, a0, vB); }

    // ---- Main: 32 steps = 8-step ring rotation x 4 (slot(o) = A[o mod 8]) ----
    #pragma unroll 1
    for (int it = 0; it < STRIP_H / 8; ++it) {
        MAINSTEP(A0, A1, A2, A3, A4, A5, A6);
        MAINSTEP(A1, A2, A3, A4, A5, A6, A7);
        MAINSTEP(A2, A3, A4, A5, A6, A7, A0);
        MAINSTEP(A3, A4, A5, A6, A7, A0, A1);
        MAINSTEP(A4, A5, A6, A7, A0, A1, A2);
        MAINSTEP(A5, A6, A7, A0, A1, A2, A3);
        MAINSTEP(A6, A7, A0, A1, A2, A3, A4);
        MAINSTEP(A7, A0, A1, A2, A3, A4, A5);
    }
}

static void fill_gauss(float* g, int k) {
    const double sigma = 0.3 * ((k - 1) * 0.5 - 1.0) + 0.8;
    double t[7], sum = 0.0;
    for (int i = 0; i < k; ++i) {
        const double x = (double)(i - k / 2);
        t[i] = exp(-x * x / (2.0 * sigma * sigma));
        sum += t[i];
    }
    for (int i = 0; i < k; ++i) g[i] = (float)(t[i] / sum);
}

extern "C" void kernel_launch(void* const* d_in, const int* in_sizes, int n_in,
                              void* d_out, int out_size, void* d_ws, size_t ws_size,
                              hipStream_t stream) {
    const float* s  = (const float*)d_in[0];
    const float* w1 = (const float*)d_in[1];
    const float* w2 = (const float*)d_in[2];
    const float* w3 = (const float*)d_in[3];
    const float* w4 = (const float*)d_in[4];
    float* out = (float*)d_out;

    const int Hd = 512, Wd = 512;
    const int planes = in_sizes[0] / (Hd * Wd);   // B*C = 192

    GaussCoefs gc;
    fill_gauss(gc.g3, 3);
    fill_gauss(gc.g5, 5);
    fill_gauss(gc.g7, 7);

    dim3 grid(1, Hd / (2 * STRIP_H), planes);     // (1, 8, 192)
    mgdf_kernel<<<grid, 256, 0, stream>>>(s, w1, w2, w3, w4, out, gc, Wd, Hd);
}

// Round 7
// 344.104 us; speedup vs baseline: 3.4127x; 1.0759x over previous
//
#include <hip/hip_runtime.h>
#include <math.h>

// Global-direct column-march multi-Gaussian fusion with TRUE software
// prefetch. R6 diagnosis: the edge-kill cndmask immediately after the row
// loads forced a vmcnt wait at LOAD time -> zero prefetch distance, every
// step paid full memory latency serially. Fix: double-buffered row loads
// (P0/P1, named regs); prefetch issues RAW loads only (no VALU touches the
// dest regs), edge-kill is applied at CONSUME time. The wait before compute
// then only covers the older buffer, keeping the new loads in flight under
// the ~270-cycle compute. STRIP_H 32->16 doubles block count for TLP.
//
// Block: 256 threads = 4 waves: (2 x-halves) x (2 y-strips of 16 rows).
// Thread: 4 cols (float4) x 16 rows, ring-of-8 named accumulators.
// Grid: (1, H/32, planes) = (1, 16, 192) = 3072 blocks.
#define STRIP_H 16

struct GaussCoefs { float g3[3]; float g5[5]; float g7[7]; };

// Wave-uniform float -> SGPR.
__device__ __forceinline__ float rfl(float x) {
    return __int_as_float(__builtin_amdgcn_readfirstlane(__float_as_int(x)));
}

#define Z4 make_float4(0.f, 0.f, 0.f, 0.f)

// acc.{xyzw} += W * F.{xyzw}
#define ADD4(A, W, F) \
    A.x = fmaf((W), (F).x, A.x); A.y = fmaf((W), (F).y, A.y); \
    A.z = fmaf((W), (F).z, A.z); A.w = fmaf((W), (F).w, A.w);

#define DOT7(a,b,c,d,e,f,g) \
    fmaf(g7h0,(a), fmaf(g7h1,(b), fmaf(g7h2,(c), fmaf(g7h3,(d), \
    fmaf(g7h4,(e), fmaf(g7h5,(f), (g7h6)*(g)))))))
#define DOT5(a,b,c,d,e) \
    fmaf(g5h0,(a), fmaf(g5h1,(b), fmaf(g5h2,(c), fmaf(g5h3,(d), (g5h4)*(e)))))
#define DOT3(a,b,c) \
    fmaf(g3h0,(a), fmaf(g3h1,(b), (g3h2)*(c)))

// Prefetch one input row into NA/NB/NC: RAW loads only. No cndmask here --
// that is the whole point (kill-at-load forces an immediate vmcnt wait).
// y-OOB rows take the wave-uniform scalar branch and get zeroed.
#define PFLOAD(NA, NB, NC) \
    if ((unsigned)row < (unsigned)Hd) { \
        const float* rp_ = sp + (size_t)row * Wd; \
        NA = *(const float4*)(rp_ + offA); \
        NB = *(const float4*)(rp_ + offB); \
        NC = *(const float4*)(rp_ + offC); \
    } else { NA = Z4; NB = Z4; NC = Z4; } \
    ++row;

// Consume the current buffer (CA,CB,CC) while prefetching the next row into
// (NA,NB,NC). Edge-kill applied here, at consume time: the vmcnt wait this
// forces covers only the OLDER loads; the just-issued ones stay in flight.
#define CSTEP(CA,CB,CC, NA,NB,NC, ...) { \
    PFLOAD(NA, NB, NC); \
    if (killA) CA = Z4; \
    if (killC) CC = Z4; \
    float4 h7, h5, h3; \
    h7.x = DOT7(CA.y,CA.z,CA.w,CB.x,CB.y,CB.z,CB.w); \
    h7.y = DOT7(CA.z,CA.w,CB.x,CB.y,CB.z,CB.w,CC.x); \
    h7.z = DOT7(CA.w,CB.x,CB.y,CB.z,CB.w,CC.x,CC.y); \
    h7.w = DOT7(CB.x,CB.y,CB.z,CB.w,CC.x,CC.y,CC.z); \
    h5.x = DOT5(CA.z,CA.w,CB.x,CB.y,CB.z); \
    h5.y = DOT5(CA.w,CB.x,CB.y,CB.z,CB.w); \
    h5.z = DOT5(CB.x,CB.y,CB.z,CB.w,CC.x); \
    h5.w = DOT5(CB.y,CB.z,CB.w,CC.x,CC.y); \
    h3.x = DOT3(CA.w,CB.x,CB.y); \
    h3.y = DOT3(CB.x,CB.y,CB.z); \
    h3.z = DOT3(CB.y,CB.z,CB.w); \
    h3.w = DOT3(CB.z,CB.w,CC.x); \
    (void)h5; (void)h3; \
    __VA_ARGS__ }

// Final consume: no prefetch.
#define CSTEP_LAST(CA,CB,CC, ...) { \
    if (killA) CA = Z4; \
    if (killC) CC = Z4; \
    float4 h7, h5, h3; \
    h7.x = DOT7(CA.y,CA.z,CA.w,CB.x,CB.y,CB.z,CB.w); \
    h7.y = DOT7(CA.z,CA.w,CB.x,CB.y,CB.z,CB.w,CC.x); \
    h7.z = DOT7(CA.w,CB.x,CB.y,CB.z,CB.w,CC.x,CC.y); \
    h7.w = DOT7(CB.x,CB.y,CB.z,CB.w,CC.x,CC.y,CC.z); \
    h5.x = DOT5(CA.z,CA.w,CB.x,CB.y,CB.z); \
    h5.y = DOT5(CA.w,CB.x,CB.y,CB.z,CB.w); \
    h5.z = DOT5(CB.x,CB.y,CB.z,CB.w,CC.x); \
    h5.w = DOT5(CB.y,CB.z,CB.w,CC.x,CC.y); \
    h3.x = DOT3(CA.w,CB.x,CB.y); \
    h3.y = DOT3(CB.x,CB.y,CB.z); \
    h3.z = DOT3(CB.y,CB.z,CB.w); \
    h3.w = DOT3(CB.z,CB.w,CC.x); \
    (void)h5; (void)h3; \
    __VA_ARGS__ }

// Steady-state scatter+store (S0 = oldest pending output, freed this step):
//   h7 -> S0..S6 (w7v6..w7v0) | h5 -> S1..S5 (w5v4..w5v0)
//   h3 -> S2..S4 (w3v2..w3v0) | s(=CB) -> S3 (a0)
#define MAINB(S0,S1,S2,S3,S4,S5,S6, CB) \
    ADD4(S0, w7v6, h7); ADD4(S1, w7v5, h7); ADD4(S2, w7v4, h7); \
    ADD4(S3, w7v3, h7); ADD4(S4, w7v2, h7); ADD4(S5, w7v1, h7); \
    ADD4(S6, w7v0, h7); \
    ADD4(S1, w5v4, h5); ADD4(S2, w5v3, h5); ADD4(S3, w5v2, h5); \
    ADD4(S4, w5v1, h5); ADD4(S5, w5v0, h5); \
    ADD4(S2, w3v2, h3); ADD4(S3, w3v1, h3); ADD4(S4, w3v0, h3); \
    ADD4(S3, a0, CB); \
    *(float4*)(op + (size_t)orow * Wd + xb) = S0; \
    S0 = Z4; ++orow;

__global__ __launch_bounds__(256, 4) void mgdf_kernel(
    const float* __restrict__ s,
    const float* __restrict__ w1p, const float* __restrict__ w2p,
    const float* __restrict__ w3p, const float* __restrict__ w4p,
    float* __restrict__ out,
    GaussCoefs gc, int Wd, int Hd)
{
    const int tid  = threadIdx.x;
    const int lane = tid & 63;
    const int xh   = (tid >> 6) & 1;    // x half (0: px 0..255, 1: 256..511)
    const int ysub = tid >> 7;          // y strip within block (0/1)
    const int plane = blockIdx.z;
    const int xb   = xh * 256 + lane * 4;
    const int ys0  = (blockIdx.y * 2 + ysub) * STRIP_H;

    const float* sp = s + (size_t)plane * Hd * Wd;
    float*       op = out + (size_t)plane * Hd * Wd;

    // Fold diff chain: (w1+w2)*s + (w3-w2)*s3 + (w4-w3)*s5 + (-w4)*s7
    const float w1 = *w1p, w2 = *w2p, w3 = *w3p, w4 = *w4p;
    const float a0v = w1 + w2, a3v = w3 - w2, a5v = w4 - w3, a7v = -w4;

    // Horizontal (unscaled) coefficients: kernarg -> SGPR already.
    const float g7h0 = gc.g7[0], g7h1 = gc.g7[1], g7h2 = gc.g7[2],
                g7h3 = gc.g7[3], g7h4 = gc.g7[4], g7h5 = gc.g7[5],
                g7h6 = gc.g7[6];
    const float g5h0 = gc.g5[0], g5h1 = gc.g5[1], g5h2 = gc.g5[2],
                g5h3 = gc.g5[3], g5h4 = gc.g5[4];
    const float g3h0 = gc.g3[0], g3h1 = gc.g3[1], g3h2 = gc.g3[2];

    // Vertical coefficients pre-scaled by fold weights; wave-uniform -> SGPR.
    const float a0   = rfl(a0v);
    const float w7v0 = rfl(a7v * g7h0), w7v1 = rfl(a7v * g7h1),
                w7v2 = rfl(a7v * g7h2), w7v3 = rfl(a7v * g7h3),
                w7v4 = rfl(a7v * g7h4), w7v5 = rfl(a7v * g7h5),
                w7v6 = rfl(a7v * g7h6);
    const float w5v0 = rfl(a5v * g5h0), w5v1 = rfl(a5v * g5h1),
                w5v2 = rfl(a5v * g5h2), w5v3 = rfl(a5v * g5h3),
                w5v4 = rfl(a5v * g5h4);
    const float w3v0 = rfl(a3v * g3h0), w3v1 = rfl(a3v * g3h1),
                w3v2 = rfl(a3v * g3h2);

    // x-halo: exactly one float4 each side; OOB only for the extreme lanes.
    // Clamp the offset at load, zero the reg at consume.
    const bool killA = (xb - 4) < 0;          // xh==0, lane 0 only
    const bool killC = (xb + 7) >= Wd;        // xh==1, lane 63 only
    const int offA = killA ? xb : (xb - 4);
    const int offB = xb;
    const int offC = killC ? xb : (xb + 4);

    int row  = ys0 - 3;   // next input row to load (global y)
    int orow = ys0;       // next output row to store (global y)

    float4 A0 = Z4, A1 = Z4, A2 = Z4, A3 = Z4,
           A4 = Z4, A5 = Z4, A6 = Z4, A7 = Z4;
    float4 p0a, p0b, p0c, p1a, p1b, p1c;

    // ---- Warm the pipe: prefetch first row ----
    PFLOAD(p0a, p0b, p0c);                       // row ys0-3

    // ---- Prologue: input rows ys0-3 .. ys0+2, partial scatter ----
    CSTEP(p0a,p0b,p0c, p1a,p1b,p1c,
      ADD4(A0, w7v0, h7); )
    CSTEP(p1a,p1b,p1c, p0a,p0b,p0c,
      ADD4(A1, w7v0, h7); ADD4(A0, w7v1, h7);
      ADD4(A0, w5v0, h5); )
    CSTEP(p0a,p0b,p0c, p1a,p1b,p1c,
      ADD4(A2, w7v0, h7); ADD4(A1, w7v1, h7); ADD4(A0, w7v2, h7);
      ADD4(A1, w5v0, h5); ADD4(A0, w5v1, h5);
      ADD4(A0, w3v0, h3); )
    CSTEP(p1a,p1b,p1c, p0a,p0b,p0c,
      ADD4(A3, w7v0, h7); ADD4(A2, w7v1, h7); ADD4(A1, w7v2, h7); ADD4(A0, w7v3, h7);
      ADD4(A2, w5v0, h5); ADD4(A1, w5v1, h5); ADD4(A0, w5v2, h5);
      ADD4(A1, w3v0, h3); ADD4(A0, w3v1, h3);
      ADD4(A0, a0, p1b); )
    CSTEP(p0a,p0b,p0c, p1a,p1b,p1c,
      ADD4(A4, w7v0, h7); ADD4(A3, w7v1, h7); ADD4(A2, w7v2, h7);
      ADD4(A1, w7v3, h7); ADD4(A0, w7v4, h7);
      ADD4(A3, w5v0, h5); ADD4(A2, w5v1, h5); ADD4(A1, w5v2, h5); ADD4(A0, w5v3, h5);
      ADD4(A2, w3v0, h3); ADD4(A1, w3v1, h3); ADD4(A0, w3v2, h3);
      ADD4(A1, a0, p0b); )
    CSTEP(p1a,p1b,p1c, p0a,p0b,p0c,
      ADD4(A5, w7v0, h7); ADD4(A4, w7v1, h7); ADD4(A3, w7v2, h7);
      ADD4(A2, w7v3, h7); ADD4(A1, w7v4, h7); ADD4(A0, w7v5, h7);
      ADD4(A4, w5v0, h5); ADD4(A3, w5v1, h5); ADD4(A2, w5v2, h5);
      ADD4(A1, w5v3, h5); ADD4(A0, w5v4, h5);
      ADD4(A3, w3v0, h3); ADD4(A2, w3v1, h3); ADD4(A1, w3v2, h3);
      ADD4(A2, a0, p1b); )

    // ---- Main: 16 steps, ring slot(o) = A[o mod 8] ----
    CSTEP(p0a,p0b,p0c, p1a,p1b,p1c, MAINB(A0,A1,A2,A3,A4,A5,A6, p0b))
    CSTEP(p1a,p1b,p1c, p0a,p0b,p0c, MAINB(A1,A2,A3,A4,A5,A6,A7, p1b))
    CSTEP(p0a,p0b,p0c, p1a,p1b,p1c, MAINB(A2,A3,A4,A5,A6,A7,A0, p0b))
    CSTEP(p1a,p1b,p1c, p0a,p0b,p0c, MAINB(A3,A4,A5,A6,A7,A0,A1, p1b))
    CSTEP(p0a,p0b,p0c, p1a,p1b,p1c, MAINB(A4,A5,A6,A7,A0,A1,A2, p0b))
    CSTEP(p1a,p1b,p1c, p0a,p0b,p0c, MAINB(A5,A6,A7,A0,A1,A2,A3, p1b))
    CSTEP(p0a,p0b,p0c, p1a,p1b,p1c, MAINB(A6,A7,A0,A1,A2,A3,A4, p0b))
    CSTEP(p1a,p1b,p1c, p0a,p0b,p0c, MAINB(A7,A0,A1,A2,A3,A4,A5, p1b))
    CSTEP(p0a,p0b,p0c, p1a,p1b,p1c, MAINB(A0,A1,A2,A3,A4,A5,A6, p0b))
    CSTEP(p1a,p1b,p1c, p0a,p0b,p0c, MAINB(A1,A2,A3,A4,A5,A6,A7, p1b))
    CSTEP(p0a,p0b,p0c, p1a,p1b,p1c, MAINB(A2,A3,A4,A5,A6,A7,A0, p0b))
    CSTEP(p1a,p1b,p1c, p0a,p0b,p0c, MAINB(A3,A4,A5,A6,A7,A0,A1, p1b))
    CSTEP(p0a,p0b,p0c, p1a,p1b,p1c, MAINB(A4,A5,A6,A7,A0,A1,A2, p0b))
    CSTEP(p1a,p1b,p1c, p0a,p0b,p0c, MAINB(A5,A6,A7,A0,A1,A2,A3, p1b))
    CSTEP(p0a,p0b,p0c, p1a,p1b,p1c, MAINB(A6,A7,A0,A1,A2,A3,A4, p0b))
    CSTEP_LAST(p1a,p1b,p1c,         MAINB(A7,A0,A1,A2,A3,A4,A5, p1b))
}

static void fill_gauss(float* g, int k) {
    const double sigma = 0.3 * ((k - 1) * 0.5 - 1.0) + 0.8;
    double t[7], sum = 0.0;
    for (int i = 0; i < k; ++i) {
        const double x = (double)(i - k / 2);
        t[i] = exp(-x * x / (2.0 * sigma * sigma));
        sum += t[i];
    }
    for (int i = 0; i < k; ++i) g[i] = (float)(t[i] / sum);
}

extern "C" void kernel_launch(void* const* d_in, const int* in_sizes, int n_in,
                              void* d_out, int out_size, void* d_ws, size_t ws_size,
                              hipStream_t stream) {
    const float* s  = (const float*)d_in[0];
    const float* w1 = (const float*)d_in[1];
    const float* w2 = (const float*)d_in[2];
    const float* w3 = (const float*)d_in[3];
    const float* w4 = (const float*)d_in[4];
    float* out = (float*)d_out;

    const int Hd = 512, Wd = 512;
    const int planes = in_sizes[0] / (Hd * Wd);   // B*C = 192

    GaussCoefs gc;
    fill_gauss(gc.g3, 3);
    fill_gauss(gc.g5, 5);
    fill_gauss(gc.g7, 7);

    dim3 grid(1, Hd / (2 * STRIP_H), planes);     // (1, 16, 192)
    mgdf_kernel<<<grid, 256, 0, stream>>>(s, w1, w2, w3, w4, out, gc, Wd, Hd);
}